// Round 5
// baseline (56.678 us; speedup 1.0000x reference)
//
#include <hip/hip_runtime.h>

constexpr int kN = 8, kC = 128, kH = 64, kW = 64, kO = 128;
constexpr int kHW = kH * kW;

typedef float f32x4 __attribute__((ext_vector_type(4)));
typedef short bf16x8 __attribute__((ext_vector_type(8)));
typedef unsigned short ushort8 __attribute__((ext_vector_type(8)));

__device__ __forceinline__ float bf2f(unsigned short u) {
  unsigned int x = ((unsigned int)u) << 16;
  return __builtin_bit_cast(float, x);
}
__device__ __forceinline__ unsigned short f2bf(float f) {
  unsigned int b = __builtin_bit_cast(unsigned int, f);
  b += 0x7FFFu + ((b >> 16) & 1u);  // RNE
  return (unsigned short)(b >> 16);
}

// ============================================================================
// prep: VERBATIM round-2 (verified passing). Per (n,h): stage [C][W] f32
// slice; per-pixel STE/BN/tanh params (f32); NHWC bf16 transposed input.
// ============================================================================
__global__ __launch_bounds__(256) void prep_kernel(
    const float* __restrict__ inp, const float* __restrict__ ste_w,
    const float* __restrict__ ste_b, const float* __restrict__ bn_g,
    const float* __restrict__ bn_b, const float* __restrict__ bn_m,
    const float* __restrict__ bn_v, unsigned short* __restrict__ nhwc,
    float* __restrict__ prm) {
  __shared__ float tile[kC * kW];     // [c][w], 32 KB
  __shared__ float part[4][3][kW];    // partial dots
  const int tid = threadIdx.x;
  const int nh = blockIdx.x;
  const int n = nh >> 6, h = nh & 63;
  const float* base = inp + (size_t)n * kC * kHW + h * kW;

  for (int i = tid; i < kC * kW; i += 256) {
    int c = i >> 6, w = i & 63;
    tile[i] = base[c * kHW + w];
  }
  __syncthreads();

  // --- params: 4 c-groups of 32, reduce in LDS ---
  {
    const int w = tid & 63, cg = tid >> 6;
    float s0 = 0.f, s1 = 0.f, s2 = 0.f;
#pragma unroll 8
    for (int j = 0; j < 32; ++j) {
      int c = cg * 32 + j;
      float v = tile[c * kW + w];
      s0 += v * ste_w[c];
      s1 += v * ste_w[kC + c];
      s2 += v * ste_w[2 * kC + c];
    }
    part[cg][0][w] = s0;
    part[cg][1][w] = s1;
    part[cg][2][w] = s2;
  }
  __syncthreads();
  if (tid < kW) {
    const int w = tid;
    float s0 = part[0][0][w] + part[1][0][w] + part[2][0][w] + part[3][0][w];
    float s1 = part[0][1][w] + part[1][1][w] + part[2][1][w] + part[3][1][w];
    float s2 = part[0][2][w] + part[1][2][w] + part[2][2][w] + part[3][2][w];
    s0 = (s0 + ste_b[0] - bn_m[0]) * (bn_g[0] * rsqrtf(bn_v[0] + 1e-5f)) + bn_b[0];
    s1 = (s1 + ste_b[1] - bn_m[1]) * (bn_g[1] * rsqrtf(bn_v[1] + 1e-5f)) + bn_b[1];
    s2 = (s2 + ste_b[2] - bn_m[2]) * (bn_g[2] * rsqrtf(bn_v[2] + 1e-5f)) + bn_b[2];
    float th = tanhf(s0) * (3.14f / 6.0f);
    float i1 = tanhf(s1) * 0.75f + 0.75f;
    float i2 = tanhf(s2) * 0.75f + 0.75f;
    float sn = sinf(th), cs = cosf(th);
    prm[nh * 192 + w * 3 + 0] = cs * i1;  // a00
    prm[nh * 192 + w * 3 + 1] = sn;       // sin
    prm[nh * 192 + w * 3 + 2] = cs * i2;  // a11
  }

  // --- NHWC bf16 write ---
  for (int i = tid; i < kW * 16; i += 256) {
    int w = i & 63, ch = i >> 6;  // ch 0..15
    int c0 = ch * 8;
    ushort8 v;
#pragma unroll
    for (int j = 0; j < 8; ++j) v[j] = f2bf(tile[(c0 + j) * kW + w]);
    *(ushort8*)&nhwc[((size_t)(n * kH + h) * kW + w) * kC + c0] = v;
  }
}

// dconv_w [O][C][3][3] -> wkb [k][O][C] bf16  (verbatim, verified)
__global__ __launch_bounds__(256) void reorder_bf16_kernel(
    const float* __restrict__ dw, unsigned short* __restrict__ wkb) {
  int idx = blockIdx.x * blockDim.x + threadIdx.x;
  if (idx >= 9 * kO * kC) return;
  int k = idx / (kO * kC);
  int r = idx - k * (kO * kC);
  int o = r >> 7, c = r & 127;
  wkb[idx] = f2bf(dw[(o * kC + c) * 9 + k]);
}

// ============================================================================
// MFMA main kernel: block = (n,h) full row. M=64 pix, N=128, K=9x128.
// 512 threads = 8 waves (4 M-groups x 2 N-groups), acc[4]. Grid = 512 blocks
// (2 resident/CU). Halves per-block-amortized B re-staging vs M=32.
// A-build math / swizzles / B-stage identical to verified round-4 code.
// ============================================================================
__global__ __launch_bounds__(512) void deform_mfma_kernel(
    const unsigned short* __restrict__ nhwc,
    const unsigned short* __restrict__ wkb,
    const float* __restrict__ prm, const float* __restrict__ db,
    float* __restrict__ out) {
  __shared__ __align__(16) unsigned short As[64 * 128];   // 16 KB, 256B rows
  __shared__ __align__(16) unsigned short Bs[128 * 128];  // 32 KB
  __shared__ float prmS[64 * 3];                          // full row

  const int tid = threadIdx.x;
  const int lane = tid & 63, wave = tid >> 6;
  const int nh = blockIdx.x;
  const int n = nh >> 6, h = nh & 63;
  const unsigned short* nhwc_n = nhwc + (size_t)n * kH * kW * kC;

  if (tid < 192) prmS[tid] = prm[nh * 192 + tid];

  const int mg = wave >> 1, ng = wave & 1;  // 4 M-groups x 2 N-groups
  const int row = mg * 16 + (lane & 15);
  const int kq = lane >> 4;
  const int rsw = (row & 7) << 4;
  f32x4 acc[4];
#pragma unroll
  for (int f = 0; f < 4; ++f) acc[f] = (f32x4){0.f, 0.f, 0.f, 0.f};

  for (int k = 0; k < 9; ++k) {
    __syncthreads();  // prmS ready (k=0); As/Bs drained (k>0)
    const float fdy = (float)(k / 3 - 1);
    const float fdx = (float)(k % 3 - 1);
    const float o0 = fdy;
    const float o1 = (k == 2) ? -1.0f : fdx;  // OFF row 2 duplicates row 0

    // ---- stage B tap tile (swizzled) ----
    const unsigned short* wkp = wkb + (size_t)k * kO * kC;
#pragma unroll
    for (int it = 0; it < 4; ++it) {
      int i = tid + it * 512;
      int o = i >> 4, ch = i & 15;
      ushort8 v = *(const ushort8*)&wkp[o * kC + ch * 8];
      *(ushort8*)((char*)Bs + o * 256 + ((ch * 16) ^ ((o & 7) << 4))) = v;
    }

    // ---- build A tap tile: 2 items/thread, verified math ----
#pragma unroll
    for (int it = 0; it < 2; ++it) {
      int i = tid + it * 512;  // [0,1024)
      int p = i >> 4, ch = i & 15;
      float a00 = prmS[p * 3], sn = prmS[p * 3 + 1], a11 = prmS[p * 3 + 2];
      float y = (float)h + fdy + o0 * a00 + o1 * sn;
      float x = (float)p + fdx - o0 * sn + o1 * a11;
      float y0f = floorf(y), x0f = floorf(x);
      float wy = y - y0f, wx = x - x0f;
      int y0 = (int)y0f, x0 = (int)x0f;
      bool yv0 = (unsigned)y0 < (unsigned)kH;
      bool yv1 = (unsigned)(y0 + 1) < (unsigned)kH;
      bool xv0 = (unsigned)x0 < (unsigned)kW;
      bool xv1 = (unsigned)(x0 + 1) < (unsigned)kW;
      int y0c = min(max(y0, 0), kH - 1);
      int y1c = min(max(y0 + 1, 0), kH - 1);
      int x0c = min(max(x0, 0), kW - 1);
      int x1c = min(max(x0 + 1, 0), kW - 1);
      float w00 = (1.f - wy) * (1.f - wx) * (yv0 && xv0 ? 1.f : 0.f);
      float w01 = (1.f - wy) * wx * (yv0 && xv1 ? 1.f : 0.f);
      float w10 = wy * (1.f - wx) * (yv1 && xv0 ? 1.f : 0.f);
      float w11 = wy * wx * (yv1 && xv1 ? 1.f : 0.f);
      const int cb = ch * 8;
      ushort8 v00 = *(const ushort8*)&nhwc_n[((y0c * kW) + x0c) * kC + cb];
      ushort8 v01 = *(const ushort8*)&nhwc_n[((y0c * kW) + x1c) * kC + cb];
      ushort8 v10 = *(const ushort8*)&nhwc_n[((y1c * kW) + x0c) * kC + cb];
      ushort8 v11 = *(const ushort8*)&nhwc_n[((y1c * kW) + x1c) * kC + cb];
      ushort8 r;
#pragma unroll
      for (int j = 0; j < 8; ++j) {
        float val = bf2f(v00[j]) * w00 + bf2f(v01[j]) * w01 +
                    bf2f(v10[j]) * w10 + bf2f(v11[j]) * w11;
        r[j] = f2bf(val);
      }
      *(ushort8*)((char*)As + p * 256 + ((ch * 16) ^ ((p & 7) << 4))) = r;
    }
    __syncthreads();

    // ---- MFMA: 16 per wave per tap ----
#pragma unroll
    for (int ks = 0; ks < 4; ++ks) {
      const int kb = ks * 64 + kq * 16;
      bf16x8 a = *(const bf16x8*)((char*)As + row * 256 + (kb ^ rsw));
#pragma unroll
      for (int f = 0; f < 4; ++f) {
        const int orow = (ng * 4 + f) * 16 + (lane & 15);
        bf16x8 b = *(const bf16x8*)((char*)Bs + orow * 256 +
                                    (kb ^ ((orow & 7) << 4)));
        acc[f] = __builtin_amdgcn_mfma_f32_16x16x32_bf16(a, b, acc[f], 0, 0, 0);
      }
    }
  }

  // ---- epilogue ----
  const int pixb = mg * 16 + (lane >> 4) * 4;
#pragma unroll
  for (int f = 0; f < 4; ++f) {
    const int o = (ng * 4 + f) * 16 + (lane & 15);
    const float bias = db[o];
    float4 v = {acc[f][0] + bias, acc[f][1] + bias, acc[f][2] + bias,
                acc[f][3] + bias};
    *(float4*)&out[((size_t)(n * kO + o)) * kHW + h * kW + pixb] = v;
  }
}

// ============================================================================
// Fallback (fp32, no workspace) — verbatim.
// ============================================================================
__global__ __launch_bounds__(256) void deform_kernel_f32(
    const float* __restrict__ inp, const float* __restrict__ ste_w,
    const float* __restrict__ ste_b, const float* __restrict__ bn_g,
    const float* __restrict__ bn_b, const float* __restrict__ bn_m,
    const float* __restrict__ bn_v, const float* __restrict__ dw,
    const float* __restrict__ db, float* __restrict__ out) {
  __shared__ __align__(16) float smp[kC * 16];
  __shared__ float prm[16][3];
  const int tid = threadIdx.x;
  const int base = blockIdx.x * 16;
  const int n = base / kHW;
  const int hw = base - n * kHW;
  const int h = hw / kW;
  const int w0 = hw - h * kW;
  const float* inp_n = inp + (size_t)n * kC * kHW;

  for (int i = tid; i < kC * 16; i += 256) {
    int c = i >> 4, p = i & 15;
    smp[i] = inp_n[c * kHW + h * kW + w0 + p];
  }
  __syncthreads();
  {
    const int p = tid >> 4, cl = tid & 15;
    float a0 = 0.f, a1 = 0.f, a2 = 0.f;
#pragma unroll
    for (int i = 0; i < 8; ++i) {
      int c = cl + (i << 4);
      float v = smp[c * 16 + p];
      a0 += v * ste_w[c];
      a1 += v * ste_w[kC + c];
      a2 += v * ste_w[2 * kC + c];
    }
#pragma unroll
    for (int off = 8; off; off >>= 1) {
      a0 += __shfl_down(a0, off, 16);
      a1 += __shfl_down(a1, off, 16);
      a2 += __shfl_down(a2, off, 16);
    }
    if (cl == 0) {
      float s0 = (a0 + ste_b[0] - bn_m[0]) * (bn_g[0] * rsqrtf(bn_v[0] + 1e-5f)) + bn_b[0];
      float s1 = (a1 + ste_b[1] - bn_m[1]) * (bn_g[1] * rsqrtf(bn_v[1] + 1e-5f)) + bn_b[1];
      float s2 = (a2 + ste_b[2] - bn_m[2]) * (bn_g[2] * rsqrtf(bn_v[2] + 1e-5f)) + bn_b[2];
      float th = tanhf(s0) * (3.14f / 6.0f);
      float i1 = tanhf(s1) * 0.75f + 0.75f;
      float i2 = tanhf(s2) * 0.75f + 0.75f;
      prm[p][0] = cosf(th) * i1;
      prm[p][1] = sinf(th);
      prm[p][2] = cosf(th) * i2;
    }
  }
  const int o = tid & 127;
  const int ph = tid >> 7;
  float acc[8] = {0.f};
  for (int k = 0; k < 9; ++k) {
    __syncthreads();
    const float fdy = (float)(k / 3 - 1);
    const float fdx = (float)(k % 3 - 1);
    const float o0 = fdy;
    const float o1 = (k == 2) ? -1.0f : fdx;
    for (int i = tid; i < kC * 16; i += 256) {
      int c = i >> 4, p = i & 15;
      float a00 = prm[p][0], sn = prm[p][1], a11 = prm[p][2];
      float y = (float)h + fdy + o0 * a00 + o1 * sn;
      float x = (float)(w0 + p) + fdx - o0 * sn + o1 * a11;
      float y0f = floorf(y), x0f = floorf(x);
      float wy = y - y0f, wx = x - x0f;
      int y0 = (int)y0f, x0 = (int)x0f;
      const float* ic = inp_n + c * kHW;
      bool yv0 = (unsigned)y0 < (unsigned)kH;
      bool yv1 = (unsigned)(y0 + 1) < (unsigned)kH;
      bool xv0 = (unsigned)x0 < (unsigned)kW;
      bool xv1 = (unsigned)(x0 + 1) < (unsigned)kW;
      int y0c = min(max(y0, 0), kH - 1);
      int y1c = min(max(y0 + 1, 0), kH - 1);
      int x0c = min(max(x0, 0), kW - 1);
      int x1c = min(max(x0 + 1, 0), kW - 1);
      float v00 = (yv0 && xv0) ? ic[y0c * kW + x0c] : 0.f;
      float v01 = (yv0 && xv1) ? ic[y0c * kW + x1c] : 0.f;
      float v10 = (yv1 && xv0) ? ic[y1c * kW + x0c] : 0.f;
      float v11 = (yv1 && xv1) ? ic[y1c * kW + x1c] : 0.f;
      smp[i] = v00 * (1.f - wy) * (1.f - wx) + v01 * (1.f - wy) * wx +
               v10 * wy * (1.f - wx) + v11 * wy * wx;
    }
    __syncthreads();
    const float* wp = dw + (size_t)o * kC * 9 + k;
#pragma unroll 4
    for (int c = 0; c < kC; ++c) {
      float wv = wp[(size_t)c * 9];
      const float4 s0 = *(const float4*)&smp[c * 16 + (ph << 3)];
      const float4 s1 = *(const float4*)&smp[c * 16 + (ph << 3) + 4];
      acc[0] += wv * s0.x; acc[1] += wv * s0.y; acc[2] += wv * s0.z; acc[3] += wv * s0.w;
      acc[4] += wv * s1.x; acc[5] += wv * s1.y; acc[6] += wv * s1.z; acc[7] += wv * s1.w;
    }
  }
  const float bias = db[o];
  float* op = out + ((size_t)(n * kO + o)) * kHW + h * kW + w0 + (ph << 3);
#pragma unroll
  for (int j = 0; j < 8; ++j) op[j] = acc[j] + bias;
}

extern "C" void kernel_launch(void* const* d_in, const int* in_sizes, int n_in,
                              void* d_out, int out_size, void* d_ws, size_t ws_size,
                              hipStream_t stream) {
  const float* inp   = (const float*)d_in[0];
  const float* ste_w = (const float*)d_in[1];
  const float* ste_b = (const float*)d_in[2];
  const float* bn_g  = (const float*)d_in[3];
  const float* bn_b  = (const float*)d_in[4];
  const float* bn_m  = (const float*)d_in[5];
  const float* bn_v  = (const float*)d_in[6];
  const float* dw    = (const float*)d_in[7];
  const float* db    = (const float*)d_in[8];
  float* out = (float*)d_out;

  // ws layout: nhwc bf16 (8 MB) | wkb bf16 (288 KB) | prm f32 (384 KB)
  const size_t nhwc_bytes = (size_t)kN * kH * kW * kC * 2;
  const size_t wkb_bytes = (size_t)9 * kO * kC * 2;
  const size_t prm_bytes = (size_t)kN * kH * kW * 3 * 4;
  const size_t need = nhwc_bytes + wkb_bytes + prm_bytes;

  if (ws_size >= need) {
    unsigned short* nhwc = (unsigned short*)d_ws;
    unsigned short* wkb = (unsigned short*)((char*)d_ws + nhwc_bytes);
    float* prm = (float*)((char*)d_ws + nhwc_bytes + wkb_bytes);
    prep_kernel<<<kN * kH, 256, 0, stream>>>(inp, ste_w, ste_b, bn_g, bn_b,
                                             bn_m, bn_v, nhwc, prm);
    int wtot = 9 * kO * kC;
    reorder_bf16_kernel<<<(wtot + 255) / 256, 256, 0, stream>>>(dw, wkb);
    deform_mfma_kernel<<<kN * kH, 512, 0, stream>>>(nhwc, wkb, prm, db, out);
  } else {
    deform_kernel_f32<<<kN * kHW / 16, 256, 0, stream>>>(
        inp, ste_w, ste_b, bn_g, bn_b, bn_m, bn_v, dw, db, out);
  }
}

// Round 6
// 51.653 us; speedup vs baseline: 1.0973x; 1.0973x over previous
//
#include <hip/hip_runtime.h>

constexpr int kN = 8, kC = 128, kH = 64, kW = 64, kO = 128;
constexpr int kHW = kH * kW;

typedef float f32x4 __attribute__((ext_vector_type(4)));
typedef short bf16x8 __attribute__((ext_vector_type(8)));
typedef unsigned short ushort8 __attribute__((ext_vector_type(8)));

__device__ __forceinline__ float bf2f(unsigned short u) {
  unsigned int x = ((unsigned int)u) << 16;
  return __builtin_bit_cast(float, x);
}
__device__ __forceinline__ unsigned short f2bf(float f) {
  unsigned int b = __builtin_bit_cast(unsigned int, f);
  b += 0x7FFFu + ((b >> 16) & 1u);  // RNE
  return (unsigned short)(b >> 16);
}

// ============================================================================
// prep: VERBATIM round-2 (verified). Per (n,h): stage [C][W] f32 slice;
// per-pixel STE/BN/tanh params (f32); NHWC bf16 transposed input.
// ============================================================================
__global__ __launch_bounds__(256) void prep_kernel(
    const float* __restrict__ inp, const float* __restrict__ ste_w,
    const float* __restrict__ ste_b, const float* __restrict__ bn_g,
    const float* __restrict__ bn_b, const float* __restrict__ bn_m,
    const float* __restrict__ bn_v, unsigned short* __restrict__ nhwc,
    float* __restrict__ prm) {
  __shared__ float tile[kC * kW];     // [c][w], 32 KB
  __shared__ float part[4][3][kW];    // partial dots
  const int tid = threadIdx.x;
  const int nh = blockIdx.x;
  const int n = nh >> 6, h = nh & 63;
  const float* base = inp + (size_t)n * kC * kHW + h * kW;

  for (int i = tid; i < kC * kW; i += 256) {
    int c = i >> 6, w = i & 63;
    tile[i] = base[c * kHW + w];
  }
  __syncthreads();

  {
    const int w = tid & 63, cg = tid >> 6;
    float s0 = 0.f, s1 = 0.f, s2 = 0.f;
#pragma unroll 8
    for (int j = 0; j < 32; ++j) {
      int c = cg * 32 + j;
      float v = tile[c * kW + w];
      s0 += v * ste_w[c];
      s1 += v * ste_w[kC + c];
      s2 += v * ste_w[2 * kC + c];
    }
    part[cg][0][w] = s0;
    part[cg][1][w] = s1;
    part[cg][2][w] = s2;
  }
  __syncthreads();
  if (tid < kW) {
    const int w = tid;
    float s0 = part[0][0][w] + part[1][0][w] + part[2][0][w] + part[3][0][w];
    float s1 = part[0][1][w] + part[1][1][w] + part[2][1][w] + part[3][1][w];
    float s2 = part[0][2][w] + part[1][2][w] + part[2][2][w] + part[3][2][w];
    s0 = (s0 + ste_b[0] - bn_m[0]) * (bn_g[0] * rsqrtf(bn_v[0] + 1e-5f)) + bn_b[0];
    s1 = (s1 + ste_b[1] - bn_m[1]) * (bn_g[1] * rsqrtf(bn_v[1] + 1e-5f)) + bn_b[1];
    s2 = (s2 + ste_b[2] - bn_m[2]) * (bn_g[2] * rsqrtf(bn_v[2] + 1e-5f)) + bn_b[2];
    float th = tanhf(s0) * (3.14f / 6.0f);
    float i1 = tanhf(s1) * 0.75f + 0.75f;
    float i2 = tanhf(s2) * 0.75f + 0.75f;
    float sn = sinf(th), cs = cosf(th);
    prm[nh * 192 + w * 3 + 0] = cs * i1;  // a00
    prm[nh * 192 + w * 3 + 1] = sn;       // sin
    prm[nh * 192 + w * 3 + 2] = cs * i2;  // a11
  }

  for (int i = tid; i < kW * 16; i += 256) {
    int w = i & 63, ch = i >> 6;
    int c0 = ch * 8;
    ushort8 v;
#pragma unroll
    for (int j = 0; j < 8; ++j) v[j] = f2bf(tile[(c0 + j) * kW + w]);
    *(ushort8*)&nhwc[((size_t)(n * kH + h) * kW + w) * kC + c0] = v;
  }
}

// dconv_w [O][C][3][3] -> wkb [k][O][C] bf16  (verbatim, verified)
__global__ __launch_bounds__(256) void reorder_bf16_kernel(
    const float* __restrict__ dw, unsigned short* __restrict__ wkb) {
  int idx = blockIdx.x * blockDim.x + threadIdx.x;
  if (idx >= 9 * kO * kC) return;
  int k = idx / (kO * kC);
  int r = idx - k * (kO * kC);
  int o = r >> 7, c = r & 127;
  wkb[idx] = f2bf(dw[(o * kC + c) * 9 + k]);
}

// ============================================================================
// MFMA main kernel: block = (n,h,w-half). M=32, N=128, K=9x128.
// 512 threads = 8 waves (2 M-groups x 4 N-groups), acc[2] — round-4 verified
// geometry. NEW: double-buffered As/Bs (80 KB, 2 blocks/CU) with a 2-phase
// pipeline: issue tap k+1's global loads BEFORE MFMA(k), interp+LDS-write
// AFTER; one barrier per tap. A-math/swizzle/epilogue identical to round 4.
// ============================================================================
__global__ __launch_bounds__(512, 4) void deform_mfma_kernel(
    const unsigned short* __restrict__ nhwc,
    const unsigned short* __restrict__ wkb,
    const float* __restrict__ prm, const float* __restrict__ db,
    float* __restrict__ out) {
  __shared__ __align__(16) unsigned short As[2][32 * 128];   // 2 x 8 KB
  __shared__ __align__(16) unsigned short Bs[2][128 * 128];  // 2 x 32 KB

  const int tid = threadIdx.x;
  const int lane = tid & 63, wave = tid >> 6;
  const int nh = blockIdx.x >> 1;
  const int w0 = (blockIdx.x & 1) << 5;
  const int n = nh >> 6, h = nh & 63;
  const unsigned short* nhwc_n = nhwc + (size_t)n * kH * kW * kC;

  // ---- per-thread fixed A-build assignment & params (p fixed => no LDS) ----
  const int p = tid >> 4, ch = tid & 15;
  const float a00 = prm[nh * 192 + (w0 + p) * 3 + 0];
  const float sn  = prm[nh * 192 + (w0 + p) * 3 + 1];
  const float a11 = prm[nh * 192 + (w0 + p) * 3 + 2];

  const int mg = wave >> 2, ng = wave & 3;  // 2 M-groups x 4 N-groups
  const int row = mg * 16 + (lane & 15);
  const int kq = lane >> 4;
  const int rsw = (row & 7) << 4;
  f32x4 acc[2];
  acc[0] = (f32x4){0.f, 0.f, 0.f, 0.f};
  acc[1] = (f32x4){0.f, 0.f, 0.f, 0.f};

  ushort8 bReg[4];            // B staging in flight
  ushort8 a00r, a01r, a10r, a11r;  // A corners in flight
  float w00, w01, w10, w11;        // bilinear weights in flight

  // issue global loads for tap k (no LDS access)
  auto issue_tap = [&](int k) {
    const unsigned short* wkp = wkb + (size_t)k * kO * kC;
#pragma unroll
    for (int it = 0; it < 4; ++it) {
      int i = tid + it * 512;
      int o = i >> 4, c8 = i & 15;
      bReg[it] = *(const ushort8*)&wkp[o * kC + c8 * 8];
    }
    const float fdy = (float)(k / 3 - 1);
    const float fdx = (float)(k % 3 - 1);
    const float o0 = fdy;
    const float o1 = (k == 2) ? -1.0f : fdx;  // OFF row 2 duplicates row 0
    float y = (float)h + fdy + o0 * a00 + o1 * sn;
    float x = (float)(w0 + p) + fdx - o0 * sn + o1 * a11;
    float y0f = floorf(y), x0f = floorf(x);
    float wy = y - y0f, wx = x - x0f;
    int y0 = (int)y0f, x0 = (int)x0f;
    bool yv0 = (unsigned)y0 < (unsigned)kH;
    bool yv1 = (unsigned)(y0 + 1) < (unsigned)kH;
    bool xv0 = (unsigned)x0 < (unsigned)kW;
    bool xv1 = (unsigned)(x0 + 1) < (unsigned)kW;
    int y0c = min(max(y0, 0), kH - 1);
    int y1c = min(max(y0 + 1, 0), kH - 1);
    int x0c = min(max(x0, 0), kW - 1);
    int x1c = min(max(x0 + 1, 0), kW - 1);
    w00 = (1.f - wy) * (1.f - wx) * (yv0 && xv0 ? 1.f : 0.f);
    w01 = (1.f - wy) * wx * (yv0 && xv1 ? 1.f : 0.f);
    w10 = wy * (1.f - wx) * (yv1 && xv0 ? 1.f : 0.f);
    w11 = wy * wx * (yv1 && xv1 ? 1.f : 0.f);
    const int cb = ch * 8;
    a00r = *(const ushort8*)&nhwc_n[((y0c * kW) + x0c) * kC + cb];
    a01r = *(const ushort8*)&nhwc_n[((y0c * kW) + x1c) * kC + cb];
    a10r = *(const ushort8*)&nhwc_n[((y1c * kW) + x0c) * kC + cb];
    a11r = *(const ushort8*)&nhwc_n[((y1c * kW) + x1c) * kC + cb];
  };

  // consume registers -> LDS tiles (swizzled, identical layout to round 4)
  auto write_tiles = [&](int buf) {
#pragma unroll
    for (int it = 0; it < 4; ++it) {
      int i = tid + it * 512;
      int o = i >> 4, c8 = i & 15;
      *(ushort8*)((char*)Bs[buf] + o * 256 + ((c8 * 16) ^ ((o & 7) << 4))) =
          bReg[it];
    }
    ushort8 r;
#pragma unroll
    for (int j = 0; j < 8; ++j) {
      float val = bf2f(a00r[j]) * w00 + bf2f(a01r[j]) * w01 +
                  bf2f(a10r[j]) * w10 + bf2f(a11r[j]) * w11;
      r[j] = f2bf(val);
    }
    *(ushort8*)((char*)As[buf] + p * 256 + ((ch * 16) ^ ((p & 7) << 4))) = r;
  };

  // ---- prologue: tap 0 ----
  issue_tap(0);
  write_tiles(0);
  __syncthreads();

  // ---- pipelined tap loop: one barrier per tap ----
  for (int k = 0; k < 9; ++k) {
    const int cur = k & 1;
    if (k < 8) issue_tap(k + 1);  // loads in flight during MFMA

    const char* Ab = (const char*)As[cur];
    const char* Bb = (const char*)Bs[cur];
#pragma unroll
    for (int ks = 0; ks < 4; ++ks) {
      const int kb = ks * 64 + kq * 16;
      bf16x8 a = *(const bf16x8*)(Ab + row * 256 + (kb ^ rsw));
#pragma unroll
      for (int f = 0; f < 2; ++f) {
        const int orow = (ng * 2 + f) * 16 + (lane & 15);
        bf16x8 b = *(const bf16x8*)(Bb + orow * 256 + (kb ^ ((orow & 7) << 4)));
        acc[f] = __builtin_amdgcn_mfma_f32_16x16x32_bf16(a, b, acc[f], 0, 0, 0);
      }
    }

    if (k < 8) write_tiles(cur ^ 1);
    __syncthreads();
  }

  // ---- epilogue (round-4 verified mapping) ----
  const int pixb = mg * 16 + (lane >> 4) * 4;
#pragma unroll
  for (int f = 0; f < 2; ++f) {
    const int o = (ng * 2 + f) * 16 + (lane & 15);
    const float bias = db[o];
    float4 v = {acc[f][0] + bias, acc[f][1] + bias, acc[f][2] + bias,
                acc[f][3] + bias};
    *(float4*)&out[((size_t)(n * kO + o)) * kHW + h * kW + w0 + pixb] = v;
  }
}

// ============================================================================
// Fallback (fp32, no workspace) — verbatim.
// ============================================================================
__global__ __launch_bounds__(256) void deform_kernel_f32(
    const float* __restrict__ inp, const float* __restrict__ ste_w,
    const float* __restrict__ ste_b, const float* __restrict__ bn_g,
    const float* __restrict__ bn_b, const float* __restrict__ bn_m,
    const float* __restrict__ bn_v, const float* __restrict__ dw,
    const float* __restrict__ db, float* __restrict__ out) {
  __shared__ __align__(16) float smp[kC * 16];
  __shared__ float prm[16][3];
  const int tid = threadIdx.x;
  const int base = blockIdx.x * 16;
  const int n = base / kHW;
  const int hw = base - n * kHW;
  const int h = hw / kW;
  const int w0 = hw - h * kW;
  const float* inp_n = inp + (size_t)n * kC * kHW;

  for (int i = tid; i < kC * 16; i += 256) {
    int c = i >> 4, p = i & 15;
    smp[i] = inp_n[c * kHW + h * kW + w0 + p];
  }
  __syncthreads();
  {
    const int p = tid >> 4, cl = tid & 15;
    float a0 = 0.f, a1 = 0.f, a2 = 0.f;
#pragma unroll
    for (int i = 0; i < 8; ++i) {
      int c = cl + (i << 4);
      float v = smp[c * 16 + p];
      a0 += v * ste_w[c];
      a1 += v * ste_w[kC + c];
      a2 += v * ste_w[2 * kC + c];
    }
#pragma unroll
    for (int off = 8; off; off >>= 1) {
      a0 += __shfl_down(a0, off, 16);
      a1 += __shfl_down(a1, off, 16);
      a2 += __shfl_down(a2, off, 16);
    }
    if (cl == 0) {
      float s0 = (a0 + ste_b[0] - bn_m[0]) * (bn_g[0] * rsqrtf(bn_v[0] + 1e-5f)) + bn_b[0];
      float s1 = (a1 + ste_b[1] - bn_m[1]) * (bn_g[1] * rsqrtf(bn_v[1] + 1e-5f)) + bn_b[1];
      float s2 = (a2 + ste_b[2] - bn_m[2]) * (bn_g[2] * rsqrtf(bn_v[2] + 1e-5f)) + bn_b[2];
      float th = tanhf(s0) * (3.14f / 6.0f);
      float i1 = tanhf(s1) * 0.75f + 0.75f;
      float i2 = tanhf(s2) * 0.75f + 0.75f;
      prm[p][0] = cosf(th) * i1;
      prm[p][1] = sinf(th);
      prm[p][2] = cosf(th) * i2;
    }
  }
  const int o = tid & 127;
  const int ph = tid >> 7;
  float acc[8] = {0.f};
  for (int k = 0; k < 9; ++k) {
    __syncthreads();
    const float fdy = (float)(k / 3 - 1);
    const float fdx = (float)(k % 3 - 1);
    const float o0 = fdy;
    const float o1 = (k == 2) ? -1.0f : fdx;
    for (int i = tid; i < kC * 16; i += 256) {
      int c = i >> 4, p = i & 15;
      float a00 = prm[p][0], sn = prm[p][1], a11 = prm[p][2];
      float y = (float)h + fdy + o0 * a00 + o1 * sn;
      float x = (float)(w0 + p) + fdx - o0 * sn + o1 * a11;
      float y0f = floorf(y), x0f = floorf(x);
      float wy = y - y0f, wx = x - x0f;
      int y0 = (int)y0f, x0 = (int)x0f;
      const float* ic = inp_n + c * kHW;
      bool yv0 = (unsigned)y0 < (unsigned)kH;
      bool yv1 = (unsigned)(y0 + 1) < (unsigned)kH;
      bool xv0 = (unsigned)x0 < (unsigned)kW;
      bool xv1 = (unsigned)(x0 + 1) < (unsigned)kW;
      int y0c = min(max(y0, 0), kH - 1);
      int y1c = min(max(y0 + 1, 0), kH - 1);
      int x0c = min(max(x0, 0), kW - 1);
      int x1c = min(max(x0 + 1, 0), kW - 1);
      float v00 = (yv0 && xv0) ? ic[y0c * kW + x0c] : 0.f;
      float v01 = (yv0 && xv1) ? ic[y0c * kW + x1c] : 0.f;
      float v10 = (yv1 && xv0) ? ic[y1c * kW + x0c] : 0.f;
      float v11 = (yv1 && xv1) ? ic[y1c * kW + x1c] : 0.f;
      smp[i] = v00 * (1.f - wy) * (1.f - wx) + v01 * (1.f - wy) * wx +
               v10 * wy * (1.f - wx) + v11 * wy * wx;
    }
    __syncthreads();
    const float* wp = dw + (size_t)o * kC * 9 + k;
#pragma unroll 4
    for (int c = 0; c < kC; ++c) {
      float wv = wp[(size_t)c * 9];
      const float4 s0 = *(const float4*)&smp[c * 16 + (ph << 3)];
      const float4 s1 = *(const float4*)&smp[c * 16 + (ph << 3) + 4];
      acc[0] += wv * s0.x; acc[1] += wv * s0.y; acc[2] += wv * s0.z; acc[3] += wv * s0.w;
      acc[4] += wv * s1.x; acc[5] += wv * s1.y; acc[6] += wv * s1.z; acc[7] += wv * s1.w;
    }
  }
  const float bias = db[o];
  float* op = out + ((size_t)(n * kO + o)) * kHW + h * kW + w0 + (ph << 3);
#pragma unroll
  for (int j = 0; j < 8; ++j) op[j] = acc[j] + bias;
}

extern "C" void kernel_launch(void* const* d_in, const int* in_sizes, int n_in,
                              void* d_out, int out_size, void* d_ws, size_t ws_size,
                              hipStream_t stream) {
  const float* inp   = (const float*)d_in[0];
  const float* ste_w = (const float*)d_in[1];
  const float* ste_b = (const float*)d_in[2];
  const float* bn_g  = (const float*)d_in[3];
  const float* bn_b  = (const float*)d_in[4];
  const float* bn_m  = (const float*)d_in[5];
  const float* bn_v  = (const float*)d_in[6];
  const float* dw    = (const float*)d_in[7];
  const float* db    = (const float*)d_in[8];
  float* out = (float*)d_out;

  const size_t nhwc_bytes = (size_t)kN * kH * kW * kC * 2;
  const size_t wkb_bytes = (size_t)9 * kO * kC * 2;
  const size_t prm_bytes = (size_t)kN * kH * kW * 3 * 4;
  const size_t need = nhwc_bytes + wkb_bytes + prm_bytes;

  if (ws_size >= need) {
    unsigned short* nhwc = (unsigned short*)d_ws;
    unsigned short* wkb = (unsigned short*)((char*)d_ws + nhwc_bytes);
    float* prm = (float*)((char*)d_ws + nhwc_bytes + wkb_bytes);
    prep_kernel<<<kN * kH, 256, 0, stream>>>(inp, ste_w, ste_b, bn_g, bn_b,
                                             bn_m, bn_v, nhwc, prm);
    int wtot = 9 * kO * kC;
    reorder_bf16_kernel<<<(wtot + 255) / 256, 256, 0, stream>>>(dw, wkb);
    deform_mfma_kernel<<<kN * kH * 2, 512, 0, stream>>>(nhwc, wkb, prm, db, out);
  } else {
    deform_kernel_f32<<<kN * kHW / 16, 256, 0, stream>>>(
        inp, ste_w, ste_b, bn_g, bn_b, bn_m, bn_v, dw, db, out);
  }
}